// Round 3
// baseline (117.615 us; speedup 1.0000x reference)
//
#include <hip/hip_runtime.h>

#pragma clang fp contract(off)

namespace {

constexpr int HD    = 96;
constexpr int STRX  = HD * HD;
constexpr int VOL   = HD * HD * HD;   // 884736 floats = 3.375 MiB per batch
constexpr int NSTEPS = 50;
constexpr int DIMI  = 95;
constexpr float DIMF = 95.0f;
constexpr float MAXC = 100.0f;
constexpr unsigned TAG = 0x5A5A0000u;
constexpr unsigned POISON = 0xAAAAAAAAu;  // harness re-poisons d_ws to 0xAA
constexpr int NSLICE = 32;

struct V3 { float x, y, z; };
struct Nb6 { const float *p0, *p1, *p2, *p3, *p4, *p5; };

__device__ __forceinline__ int clampi(int v) {
    return v < 0 ? 0 : (v > DIMI ? DIMI : v);
}

__device__ __forceinline__ int xcc_id() {
    unsigned v;
    asm volatile("s_getreg_b32 %0, hwreg(HW_REG_XCC_ID)" : "=s"(v));
    return (int)(v & 0xFu);
}

// Addresses of the 6 central-difference neighbors of the voxel p maps to
// (idx = clip(trunc(p*95), 0, 95), edge-padded).
__device__ __forceinline__ Nb6 nb_addr(const float* __restrict__ base, V3 p) {
    int x = clampi((int)(p.x * DIMF));
    int y = clampi((int)(p.y * DIMF));
    int z = clampi((int)(p.z * DIMF));
    int xp = x < DIMI ? x + 1 : DIMI, xm = x > 0 ? x - 1 : 0;
    int yp = y < DIMI ? y + 1 : DIMI, ym = y > 0 ? y - 1 : 0;
    int zp = z < DIMI ? z + 1 : DIMI, zm = z > 0 ? z - 1 : 0;
    int rowx = x * STRX, coly = y * HD;
    Nb6 r;
    r.p0 = base + (xp * STRX + coly + z);
    r.p1 = base + (xm * STRX + coly + z);
    r.p2 = base + (rowx + yp * HD + z);
    r.p3 = base + (rowx + ym * HD + z);
    r.p4 = base + (rowx + coly + zp);
    r.p5 = base + (rowx + coly + zm);
    return r;
}

// a_i = -(2 v_i (g.v) - g_i |v|^2), clipped to +-100 (collapsed einsum;
// formula kept bit-identical to the R0/R1 version that matched numpy exactly)
__device__ __forceinline__ V3 accel6(float n0, float n1, float n2, float n3,
                                     float n4, float n5, V3 v) {
    float gx = (n0 - n1) * 0.5f;
    float gy = (n2 - n3) * 0.5f;
    float gz = (n4 - n5) * 0.5f;
    float gv = gx * v.x + gy * v.y + gz * v.z;
    float vv = v.x * v.x + v.y * v.y + v.z * v.z;
    V3 a;
    a.x = -(2.0f * v.x * gv - gx * vv);
    a.y = -(2.0f * v.y * gv - gy * vv);
    a.z = -(2.0f * v.z * gv - gz * vv);
    a.x = fminf(fmaxf(a.x, -MAXC), MAXC);
    a.y = fminf(fmaxf(a.y, -MAXC), MAXC);
    a.z = fminf(fmaxf(a.z, -MAXC), MAXC);
    return a;
}

__device__ __forceinline__ V3 axpy(V3 a, float s, V3 b) {
    V3 r; r.x = a.x + s * b.x; r.y = a.y + s * b.y; r.z = a.z + s * b.z;
    return r;
}

// One wave cooperatively warms slices of a batch volume into this XCD's L2.
// Slice ownership via poison-aware atomic counter: counter starts at POISON
// (harness re-poisons ws each launch); claimed index = fetch_add - POISON.
__device__ __forceinline__ void warm_wave(const float* __restrict__ base,
                                          unsigned* __restrict__ ctr, int lane) {
    const float4* p4 = (const float4*)base;
    const int per = (VOL / 4) / NSLICE;   // 221184/32 = 6912 float4 per slice
    float acc = 0.f;
    for (;;) {
        unsigned old = 0;
        if (lane == 0)
            old = __hip_atomic_fetch_add(ctr, 1u, __ATOMIC_RELAXED,
                                         __HIP_MEMORY_SCOPE_AGENT);
        old = __shfl(old, 0);
        unsigned s = old - POISON;        // wraps; valid slices are 0..NSLICE-1
        if (s >= (unsigned)NSLICE) break;
        int lo = (int)s * per;
        for (int i = lo + lane; i < lo + per; i += 64) {
            float4 v = p4[i];
            acc += v.x + v.y + v.z + v.w;
        }
    }
    asm volatile("" :: "v"(acc));          // keep loads live (no DCE)
}

} // namespace

// launch_bounds(256, 1): 1 wave/EU minimum -> full 512-VGPR budget so the
// scheduler can keep all 12 loads of a round in flight (R2 had VGPR=20 ->
// serialized rounds).
__global__ void __launch_bounds__(256, 1)
geodesic_kernel(const float* __restrict__ sp, const float* __restrict__ sv,
                const float* __restrict__ Phi, float* __restrict__ out,
                int B, unsigned* __restrict__ ws) {
    int xcc = xcc_id();
    int lane = threadIdx.x & 63;

    if (blockIdx.x < (unsigned)B) {
        // ================= integrator block for batch b =================
        int b = blockIdx.x;
        const float* __restrict__ base = Phi + (long)b * VOL;

        if (threadIdx.x == 0) {
            // publish my XCD so helpers on the same XCD warm my volume
            __hip_atomic_store(&ws[b], TAG | (unsigned)xcc,
                               __ATOMIC_RELAXED, __HIP_MEMORY_SCOPE_AGENT);
        }
        if (threadIdx.x >= 64) {
            // waves 1..3: join the slice pool for my batch (same CU -> same L2)
            warm_wave(base, &ws[2 + b], lane);
            return;
        }
        if (threadIdx.x != 0) return;

        __builtin_amdgcn_s_setprio(1);     // latency-critical serial wave

        const float H   = 0.1f;
        const float H05 = 0.5f * H;
        const float H6  = (float)(0.1 / 6.0);

        float* __restrict__ opos = out;                        // (B,50,3)
        float* __restrict__ ovel = out + (long)B * NSTEPS * 3; // (B,50,3)

        V3 pos = { sp[b * 3 + 0], sp[b * 3 + 1], sp[b * 3 + 2] };
        V3 vel = { sv[b * 3 + 0], sv[b * 3 + 1], sv[b * 3 + 2] };

        long o0 = (long)b * NSTEPS * 3;
        opos[o0 + 0] = pos.x; opos[o0 + 1] = pos.y; opos[o0 + 2] = pos.z;
        ovel[o0 + 0] = vel.x; ovel[o0 + 1] = vel.y; ovel[o0 + 2] = vel.z;

        for (int t = 1; t < NSTEPS; ++t) {
            // ---- round A: p1, p2 known up-front; 12 addrs, then 12 loads ----
            V3 p1 = pos;
            V3 p2 = axpy(pos, H05, vel);
            Nb6 A = nb_addr(base, p1);
            Nb6 Bq = nb_addr(base, p2);
            float a0 = *A.p0,  a1 = *A.p1,  a2 = *A.p2,
                  a3 = *A.p3,  a4 = *A.p4,  a5 = *A.p5;
            float b0 = *Bq.p0, b1 = *Bq.p1, b2 = *Bq.p2,
                  b3 = *Bq.p3, b4 = *Bq.p4, b5 = *Bq.p5;

            V3 k1a = accel6(a0, a1, a2, a3, a4, a5, vel);
            V3 k2v = axpy(vel, H05, k1a);
            V3 k2a = accel6(b0, b1, b2, b3, b4, b5, k2v);
            V3 k3v = axpy(vel, H05, k2a);

            // ---- round B: p3 needs k1a, p4 needs k2a; again 12+12 ----
            V3 p3 = axpy(pos, H05, k2v);
            V3 p4 = axpy(pos, H, k3v);
            Nb6 C = nb_addr(base, p3);
            Nb6 D = nb_addr(base, p4);
            float c0 = *C.p0, c1 = *C.p1, c2 = *C.p2,
                  c3 = *C.p3, c4 = *C.p4, c5 = *C.p5;
            float d0 = *D.p0, d1 = *D.p1, d2 = *D.p2,
                  d3 = *D.p3, d4 = *D.p4, d5 = *D.p5;

            V3 k3a = accel6(c0, c1, c2, c3, c4, c5, k3v);
            V3 k4v = axpy(vel, H, k3a);
            V3 k4a = accel6(d0, d1, d2, d3, d4, d5, k4v);

            V3 sv_;
            sv_.x = vel.x + 2.0f * k2v.x + 2.0f * k3v.x + k4v.x;
            sv_.y = vel.y + 2.0f * k2v.y + 2.0f * k3v.y + k4v.y;
            sv_.z = vel.z + 2.0f * k2v.z + 2.0f * k3v.z + k4v.z;
            V3 sa;
            sa.x = k1a.x + 2.0f * k2a.x + 2.0f * k3a.x + k4a.x;
            sa.y = k1a.y + 2.0f * k2a.y + 2.0f * k3a.y + k4a.y;
            sa.z = k1a.z + 2.0f * k2a.z + 2.0f * k3a.z + k4a.z;
            pos = axpy(pos, H6, sv_);
            vel = axpy(vel, H6, sa);

            long ot = (long)b * NSTEPS * 3 + (long)t * 3;
            opos[ot + 0] = pos.x; opos[ot + 1] = pos.y; opos[ot + 2] = pos.z;
            ovel[ot + 0] = vel.x; ovel[ot + 1] = vel.y; ovel[ot + 2] = vel.z;
        }
        return;
    }

    // ================= helper blocks: warm the matching XCD's L2 =============
    unsigned w0 = 0, w1 = 0;
    if (lane == 0) {
        for (int it = 0; it < 65536; ++it) {
            w0 = __hip_atomic_load(&ws[0], __ATOMIC_RELAXED,
                                   __HIP_MEMORY_SCOPE_AGENT);
            w1 = __hip_atomic_load(&ws[1], __ATOMIC_RELAXED,
                                   __HIP_MEMORY_SCOPE_AGENT);
            if ((w0 & 0xFFFF0000u) == TAG && (w1 & 0xFFFF0000u) == TAG) break;
        }
    }
    w0 = __shfl(w0, 0);
    w1 = __shfl(w1, 0);
    int t0 = ((w0 & 0xFFFF0000u) == TAG) ? (int)(w0 & 0xFu) : -1;
    int t1 = ((w1 & 0xFFFF0000u) == TAG) ? (int)(w1 & 0xFu) : -1;

    int batch = -1;
    if (xcc == t0 && xcc == t1)      batch = (int)(blockIdx.x & 1);
    else if (xcc == t0)              batch = 0;
    else if (xcc == t1)              batch = 1;
    if (batch < 0) return;

    warm_wave(Phi + (long)batch * VOL, &ws[2 + batch], lane);
}

extern "C" void kernel_launch(void* const* d_in, const int* in_sizes, int n_in,
                              void* d_out, int out_size, void* d_ws, size_t ws_size,
                              hipStream_t stream) {
    const float* sp  = (const float*)d_in[0];
    const float* sv  = (const float*)d_in[1];
    const float* phi = (const float*)d_in[2];
    float* out = (float*)d_out;
    unsigned* ws = (unsigned*)d_ws;
    int B = in_sizes[0] / 3;   // = 2

    geodesic_kernel<<<dim3(B + 126), dim3(256), 0, stream>>>(sp, sv, phi, out, B, ws);
}